// Round 10
// baseline (163.239 us; speedup 1.0000x reference)
//
#include <hip/hip_runtime.h>
#include <math.h>

#define NN 8192
#define L2E 1.44269504088896340736f
#define TWO_PI 6.28318530717958647693f

typedef _Float16 h8 __attribute__((ext_vector_type(8)));
typedef _Float16 h4 __attribute__((ext_vector_type(4)));
typedef float f32x4 __attribute__((ext_vector_type(4)));
typedef float f32x2 __attribute__((ext_vector_type(2)));
typedef unsigned int u32x4 __attribute__((ext_vector_type(4)));
#define MFMA16(A, B, C) __builtin_amdgcn_mfma_f32_16x16x32_f16(A, B, C, 0, 0, 0)

// async 16B-per-lane global->LDS DMA; LDS dest is wave-uniform base + lane*16
#define GLD_LDS16(gsrc, ldst)                                          \
  __builtin_amdgcn_global_load_lds(                                    \
      (const __attribute__((address_space(1))) unsigned int*)(gsrc),   \
      (__attribute__((address_space(3))) unsigned int*)(ldst), 16, 0, 0)

union V8 { float4 v[2]; float f[8]; };

// ---------------------------------------------------------------------------
// prep: eta_s = eta*s, phi_s = phi*s (s = sqrt(alpha*log2e));
// H1 = relu(x@W1+b1) f32 row-major + f16 transposed [64][NN]. 32 rows/block.
// ---------------------------------------------------------------------------
__global__ __launch_bounds__(256) void prep_kernel(
    const float* __restrict__ x, const float* __restrict__ alpha,
    const float* __restrict__ W1, const float* __restrict__ b1,
    float* __restrict__ eta_s, float* __restrict__ phi_s,
    float* __restrict__ H1, _Float16* __restrict__ HT1,
    float* __restrict__ svec)
{
  __shared__ float sW[448];
  __shared__ float sb[64];
  __shared__ float T[32][68];
  const int t = threadIdx.x;
  if (blockIdx.x == 0 && t < 64) svec[t] = 0.f;
  for (int k = t; k < 448; k += 256) sW[k] = W1[k];
  if (t < 64) sb[t] = b1[t];
  const float s = sqrtf(alpha[0] * L2E);
  const int i0 = blockIdx.x * 32;
  const int r = t >> 3, q = t & 7;
  const int i = i0 + r;
  float xv[7];
#pragma unroll
  for (int k = 0; k < 7; k++) xv[k] = x[i * 7 + k];
  if (q == 0) { eta_s[i] = xv[1] * s; phi_s[i] = xv[2] * s; }
  __syncthreads();
#pragma unroll
  for (int c = 0; c < 8; c++) {
    const int n = q * 8 + c;
    float hv = sb[n];
#pragma unroll
    for (int k = 0; k < 7; k++) hv = fmaf(xv[k], sW[k * 64 + n], hv);
    T[r][n] = fmaxf(hv, 0.f);
  }
  __syncthreads();
  for (int e = t; e < 512; e += 256)
    *(f32x4*)(H1 + (size_t)i0 * 64 + (e << 2)) =
        *(const f32x4*)&T[e >> 4][(e << 2) & 63];
  const int n = t >> 2, sg = (t & 3) * 8;
  h8 v;
#pragma unroll
  for (int ss = 0; ss < 8; ss++) v[ss] = (_Float16)T[sg + ss][n];
  *(h8*)(HT1 + (size_t)n * NN + i0 + sg) = v;
}

// ---------------------------------------------------------------------------
// attn: 32 i-rows/block, 4-way j-split (grid 1024). 16 stages of 128 j; HT
// chunk staged via global_load_lds into XOR-swizzled LDS. SUPERSTAGE: each
// LDS buffer holds TWO stages (32 KB), double-buffered (64 KB) -> ONE
// barrier per 2 stages (8/block instead of 16). 2 blocks/CU (same effective
// occupancy as before), VGPR headroom to ~256 at 2 waves/SIMD.
// PASS1: pv chain -> f16 pack (MFMA: Y1 += P@HT, l via ones-MFMA) + fp8
//        pack -> coalesced fragment-stream store to Pm8 (64 MB).
// PASS2: pure GEMM — fp8 frags reloaded, expanded on VALU, prefetched.
// ---------------------------------------------------------------------------
template <bool PASS1>
__global__ __launch_bounds__(256, 2) void attn_pass(
    const float* __restrict__ eta_s, const float* __restrict__ phi_s,
    const _Float16* __restrict__ HT, const float* __restrict__ alpha,
    unsigned char* __restrict__ Pm8,
    float* __restrict__ Ypart, float* __restrict__ lpart)
{
  __shared__ __align__(16) char smem[65536];  // 2 pairs x 2 stages x 16 KB
  _Float16* const stage = (_Float16*)smem;
  const int tid = threadIdx.x;
  const int w = tid >> 6, lane = tid & 63, m = lane & 15, g = lane >> 4;
  const int tile = blockIdx.x >> 2, part = blockIdx.x & 3;
  const int i0 = tile << 5;
  const int jbase = part << 11;
  const int jcol0 = jbase + (w << 5) + (g << 3);  // this lane's j-group base

  // staging geometry: slot d = k*256+tid holds HT row (k*16 + tid>>4),
  // swizzled j-group ((tid&15) ^ (tid>>4)). Same swizzle offset for all k.
  const int r0 = tid >> 4, gq = tid & 15;
  const _Float16* sbase = HT + (size_t)r0 * NN + ((gq ^ r0) << 3) + jbase;

  f32x4 a00 = {0,0,0,0}, a01 = {0,0,0,0}, a02 = {0,0,0,0}, a03 = {0,0,0,0};
  f32x4 a10 = {0,0,0,0}, a11 = {0,0,0,0}, a12 = {0,0,0,0}, a13 = {0,0,0,0};
  f32x4 l0a = {0,0,0,0}, l1a = {0,0,0,0};
  const h8 onesv = {(_Float16)1.f, (_Float16)1.f, (_Float16)1.f, (_Float16)1.f,
                    (_Float16)1.f, (_Float16)1.f, (_Float16)1.f, (_Float16)1.f};

  // fp8 fragment-stream base: block*(16 stages * 4 KB) + wave*1 KB + lane*16B
  unsigned char* const pfb8 =
      Pm8 + ((size_t)blockIdx.x * 16) * 4096 + (w << 10) + (lane << 4);

  // stage t lives at half-offset (((t>>1)&1)<<14) | ((t&1)<<13)
  auto soff = [](int t) { return (((t >> 1) & 1) << 14) | ((t & 1) << 13); };

  // PASS1 state: eta/phi of i-rows + register-prefetched j-slices
  float Cs = 0.f, et0 = 0.f, ph0 = 0.f, et1 = 0.f, ph1 = 0.f;
  const float* ep = nullptr;
  const float* pp = nullptr;
  V8 Ec0, Pc0, Ec1, Pc1, En0, Pn0, En1, Pn1;
  // PASS2 state: register-prefetched fp8 A-frags (2 stages in flight)
  u32x4 c80, c81, n80, n81;
  if constexpr (PASS1) {
    Cs = TWO_PI * sqrtf(alpha[0] * L2E);
    et0 = eta_s[i0 + m];      ph0 = phi_s[i0 + m];
    et1 = eta_s[i0 + 16 + m]; ph1 = phi_s[i0 + 16 + m];
    ep = eta_s + jcol0;
    pp = phi_s + jcol0;
    Ec0.v[0] = *(const float4*)ep;          Ec0.v[1] = *(const float4*)(ep + 4);
    Pc0.v[0] = *(const float4*)pp;          Pc0.v[1] = *(const float4*)(pp + 4);
    Ec1.v[0] = *(const float4*)(ep + 128);  Ec1.v[1] = *(const float4*)(ep + 132);
    Pc1.v[0] = *(const float4*)(pp + 128);  Pc1.v[1] = *(const float4*)(pp + 132);
  } else {
    c80 = *(const u32x4*)(pfb8);
    c81 = *(const u32x4*)(pfb8 + 4096);
  }

  // prologue: stages 0,1 -> pair 0
#pragma unroll
  for (int t = 0; t < 2; ++t)
#pragma unroll
    for (int k = 0; k < 4; ++k)
      GLD_LDS16(sbase + t * 128 + (size_t)k * 16 * NN,
                stage + soff(t) + ((k * 256 + tid) << 3));
  __syncthreads();

  // frag slot (nb=0): row block m, swizzled j-group (w*4+g)^m
  const int fs = ((m << 4) + (((w << 2) | g) ^ m)) << 3;

  union AF { h8 v; decltype(__builtin_amdgcn_cvt_pkrtz(0.f, 0.f)) p[4]; };

  // PASS1 body: pv chain -> f16 pack (MFMA) + fp8 pack (store) -> MFMA (+l)
  auto stage_compute = [&](const V8& Ec, const V8& Pc, const _Float16* cur,
                           int sIdx) {
    const h8 b0 = *(const h8*)(cur + fs);
    const h8 b1 = *(const h8*)(cur + 2048 + fs);
    const h8 b2 = *(const h8*)(cur + 4096 + fs);
    const h8 b3 = *(const h8*)(cur + 6144 + fs);
    AF af0, af1;
    float pva[8], pvb[8];
#pragma unroll
    for (int tt = 0; tt < 8; tt += 2) {
      const f32x2 pj = {Pc.f[tt], Pc.f[tt + 1]};
      const f32x2 ej = {Ec.f[tt], Ec.f[tt + 1]};
      const f32x2 dp0 = ph0 - pj, dp1 = ph1 - pj;
      const f32x2 ad0 = {fabsf(dp0.x), fabsf(dp0.y)};
      const f32x2 ad1 = {fabsf(dp1.x), fabsf(dp1.y)};
      const f32x2 cm0 = Cs - ad0, cm1 = Cs - ad1;
      const f32x2 wr0 = {fminf(ad0.x, cm0.x), fminf(ad0.y, cm0.y)};
      const f32x2 wr1 = {fminf(ad1.x, cm1.x), fminf(ad1.y, cm1.y)};
      const f32x2 de0 = et0 - ej, de1 = et1 - ej;
      const f32x2 r20 = de0 * de0 + wr0 * wr0;
      const f32x2 r21 = de1 * de1 + wr1 * wr1;
      const f32x2 ax0 = {__builtin_amdgcn_exp2f(-r20.x),
                         __builtin_amdgcn_exp2f(-r20.y)};
      const f32x2 ax1 = {__builtin_amdgcn_exp2f(-r21.x),
                         __builtin_amdgcn_exp2f(-r21.y)};
      const f32x2 ga0 = ax0 * L2E - L2E;
      const f32x2 ga1 = ax1 * L2E - L2E;
      const float va0 = __builtin_amdgcn_exp2f(ga0.x);
      const float va1 = __builtin_amdgcn_exp2f(ga0.y);
      const float vb0 = __builtin_amdgcn_exp2f(ga1.x);
      const float vb1 = __builtin_amdgcn_exp2f(ga1.y);
      pva[tt] = va0; pva[tt + 1] = va1;
      pvb[tt] = vb0; pvb[tt + 1] = vb1;
      af0.p[tt >> 1] = __builtin_amdgcn_cvt_pkrtz(va0, va1);
      af1.p[tt >> 1] = __builtin_amdgcn_cvt_pkrtz(vb0, vb1);
    }
    unsigned int ra0 = __builtin_amdgcn_cvt_pk_fp8_f32(pva[0], pva[1], 0, false);
    ra0 = __builtin_amdgcn_cvt_pk_fp8_f32(pva[2], pva[3], ra0, true);
    unsigned int ra1 = __builtin_amdgcn_cvt_pk_fp8_f32(pva[4], pva[5], 0, false);
    ra1 = __builtin_amdgcn_cvt_pk_fp8_f32(pva[6], pva[7], ra1, true);
    unsigned int rb0 = __builtin_amdgcn_cvt_pk_fp8_f32(pvb[0], pvb[1], 0, false);
    rb0 = __builtin_amdgcn_cvt_pk_fp8_f32(pvb[2], pvb[3], rb0, true);
    unsigned int rb1 = __builtin_amdgcn_cvt_pk_fp8_f32(pvb[4], pvb[5], 0, false);
    rb1 = __builtin_amdgcn_cvt_pk_fp8_f32(pvb[6], pvb[7], rb1, true);
    const u32x4 r8 = {ra0, ra1, rb0, rb1};
    *(u32x4*)(pfb8 + sIdx * 4096) = r8;
    __builtin_amdgcn_s_setprio(1);
    a00 = MFMA16(af0.v, b0, a00); a01 = MFMA16(af0.v, b1, a01);
    a02 = MFMA16(af0.v, b2, a02); a03 = MFMA16(af0.v, b3, a03);
    a10 = MFMA16(af1.v, b0, a10); a11 = MFMA16(af1.v, b1, a11);
    a12 = MFMA16(af1.v, b2, a12); a13 = MFMA16(af1.v, b3, a13);
    l0a = MFMA16(af0.v, onesv, l0a);
    l1a = MFMA16(af1.v, onesv, l1a);
    __builtin_amdgcn_s_setprio(0);
  };

  // PASS2 body: fp8 frags -> f32 -> f16 on VALU, then 8 MFMAs
  auto stage_gemm = [&](u32x4 r8, const _Float16* cur) {
    const h8 b0 = *(const h8*)(cur + fs);
    const h8 b1 = *(const h8*)(cur + 2048 + fs);
    const h8 b2 = *(const h8*)(cur + 4096 + fs);
    const h8 b3 = *(const h8*)(cur + 6144 + fs);
    AF af0, af1;
    {
      const f32x2 c01 = __builtin_amdgcn_cvt_pk_f32_fp8(r8.x, false);
      const f32x2 c23 = __builtin_amdgcn_cvt_pk_f32_fp8(r8.x, true);
      const f32x2 c45 = __builtin_amdgcn_cvt_pk_f32_fp8(r8.y, false);
      const f32x2 c67 = __builtin_amdgcn_cvt_pk_f32_fp8(r8.y, true);
      af0.p[0] = __builtin_amdgcn_cvt_pkrtz(c01.x, c01.y);
      af0.p[1] = __builtin_amdgcn_cvt_pkrtz(c23.x, c23.y);
      af0.p[2] = __builtin_amdgcn_cvt_pkrtz(c45.x, c45.y);
      af0.p[3] = __builtin_amdgcn_cvt_pkrtz(c67.x, c67.y);
    }
    {
      const f32x2 c01 = __builtin_amdgcn_cvt_pk_f32_fp8(r8.z, false);
      const f32x2 c23 = __builtin_amdgcn_cvt_pk_f32_fp8(r8.z, true);
      const f32x2 c45 = __builtin_amdgcn_cvt_pk_f32_fp8(r8.w, false);
      const f32x2 c67 = __builtin_amdgcn_cvt_pk_f32_fp8(r8.w, true);
      af1.p[0] = __builtin_amdgcn_cvt_pkrtz(c01.x, c01.y);
      af1.p[1] = __builtin_amdgcn_cvt_pkrtz(c23.x, c23.y);
      af1.p[2] = __builtin_amdgcn_cvt_pkrtz(c45.x, c45.y);
      af1.p[3] = __builtin_amdgcn_cvt_pkrtz(c67.x, c67.y);
    }
    __builtin_amdgcn_s_setprio(1);
    a00 = MFMA16(af0.v, b0, a00); a01 = MFMA16(af0.v, b1, a01);
    a02 = MFMA16(af0.v, b2, a02); a03 = MFMA16(af0.v, b3, a03);
    a10 = MFMA16(af1.v, b0, a10); a11 = MFMA16(af1.v, b1, a11);
    a12 = MFMA16(af1.v, b2, a12); a13 = MFMA16(af1.v, b3, a13);
    __builtin_amdgcn_s_setprio(0);
  };

#pragma unroll
  for (int sb = 0; sb < 8; ++sb) {
    const int s0 = 2 * sb, s1 = 2 * sb + 1;
    if (sb < 7) {  // prefetch stages s0+2, s1+2 into the other pair
#pragma unroll
      for (int t = 0; t < 2; ++t) {
        const int ts = s0 + 2 + t;
        const _Float16* src = sbase + ts * 128;
#pragma unroll
        for (int k = 0; k < 4; ++k)
          GLD_LDS16(src + (size_t)k * 16 * NN,
                    stage + soff(ts) + ((k * 256 + tid) << 3));
      }
      if constexpr (PASS1) {
        En0.v[0] = *(const float4*)(ep + (s0 + 2) * 128);
        En0.v[1] = *(const float4*)(ep + (s0 + 2) * 128 + 4);
        Pn0.v[0] = *(const float4*)(pp + (s0 + 2) * 128);
        Pn0.v[1] = *(const float4*)(pp + (s0 + 2) * 128 + 4);
        En1.v[0] = *(const float4*)(ep + (s1 + 2) * 128);
        En1.v[1] = *(const float4*)(ep + (s1 + 2) * 128 + 4);
        Pn1.v[0] = *(const float4*)(pp + (s1 + 2) * 128);
        Pn1.v[1] = *(const float4*)(pp + (s1 + 2) * 128 + 4);
      } else {
        n80 = *(const u32x4*)(pfb8 + (s0 + 2) * 4096);
        n81 = *(const u32x4*)(pfb8 + (s1 + 2) * 4096);
      }
    }
    if constexpr (PASS1) {
      stage_compute(Ec0, Pc0, stage + soff(s0), s0);
      stage_compute(Ec1, Pc1, stage + soff(s1), s1);
      Ec0 = En0; Pc0 = Pn0; Ec1 = En1; Pc1 = Pn1;
    } else {
      stage_gemm(c80, stage + soff(s0));
      stage_gemm(c81, stage + soff(s1));
      c80 = n80; c81 = n81;
    }
    __syncthreads();  // drains prefetch + all frag reads of this pair
  }

  // cross-wave reduction (aliases stage; all stage reads completed above).
  // D layout: col = lane&15, row = (lane>>4)*4 + reg. Col 64 carries l
  // (= rowsum from the ones-MFMA; identical across lanes m, so m==0 writes).
  typedef float Red2[32][66];
  Red2* red = (Red2*)smem;                  // 2 x 8448 B
  const int h = w >> 1;
  if ((w & 1) == 0) {
#pragma unroll
    for (int r = 0; r < 4; ++r) {
      red[h][g * 4 + r][m]      = a00[r]; red[h][g * 4 + r][16 + m] = a01[r];
      red[h][g * 4 + r][32 + m] = a02[r]; red[h][g * 4 + r][48 + m] = a03[r];
      red[h][16 + g * 4 + r][m]      = a10[r]; red[h][16 + g * 4 + r][16 + m] = a11[r];
      red[h][16 + g * 4 + r][32 + m] = a12[r]; red[h][16 + g * 4 + r][48 + m] = a13[r];
    }
    if constexpr (PASS1) {
      if (m == 0) {
#pragma unroll
        for (int r = 0; r < 4; ++r) {
          red[h][g * 4 + r][64]      = l0a[r];
          red[h][16 + g * 4 + r][64] = l1a[r];
        }
      }
    }
  }
  __syncthreads();
  if (w & 1) {
#pragma unroll
    for (int r = 0; r < 4; ++r) {
      red[h][g * 4 + r][m]      += a00[r]; red[h][g * 4 + r][16 + m] += a01[r];
      red[h][g * 4 + r][32 + m] += a02[r]; red[h][g * 4 + r][48 + m] += a03[r];
      red[h][16 + g * 4 + r][m]      += a10[r]; red[h][16 + g * 4 + r][16 + m] += a11[r];
      red[h][16 + g * 4 + r][32 + m] += a12[r]; red[h][16 + g * 4 + r][48 + m] += a13[r];
    }
    if constexpr (PASS1) {
      if (m == 0) {
#pragma unroll
        for (int r = 0; r < 4; ++r) {
          red[h][g * 4 + r][64]      += l0a[r];
          red[h][16 + g * 4 + r][64] += l1a[r];
        }
      }
    }
  }
  __syncthreads();
#pragma unroll
  for (int k = 0; k < 8; ++k) {
    const int e = tid + k * 256;
    Ypart[((size_t)part * NN + i0 + (e >> 6)) * 64 + (e & 63)] =
        red[0][e >> 6][e & 63] + red[1][e >> 6][e & 63];
  }
  if constexpr (PASS1) {
    if (tid < 32)
      lpart[(size_t)part * NN + i0 + tid] = red[0][tid][64] + red[1][tid][64];
  }
}

// ---------------------------------------------------------------------------
// mid: U = sum(Ypart)/l + H1 ; Z = relu(U@wt1+bs1) ; H2 = relu(Z@W2+b2)
// 16 rows/block, grid 512. U rows read as ds_read_b128 (U padded to [68]).
// ---------------------------------------------------------------------------
__global__ __launch_bounds__(256) void mid_kernel(
    const float* __restrict__ Yp, const float* __restrict__ lp,
    const float* __restrict__ H1, const float* __restrict__ wt1,
    const float* __restrict__ bs1, const float* __restrict__ W2,
    const float* __restrict__ b2, float* __restrict__ H2,
    _Float16* __restrict__ HT2)
{
  __shared__ float sA[64][68];
  __shared__ float sB[64][68];
  __shared__ float U[16][68];
  __shared__ float sb2v[64];
  const int t = threadIdx.x;
  for (int e = t; e < 1024; e += 256) {
    const int rr = e >> 4, cc = (e << 2) & 63;
    *(f32x4*)&sA[rr][cc] = *(const f32x4*)(wt1 + (e << 2));
    *(f32x4*)&sB[rr][cc] = *(const f32x4*)(W2 + (e << 2));
  }
  if (t < 64) sb2v[t] = b2[t];
  const float bsv = bs1[0];
  const int i0 = blockIdx.x * 16;
  const int r = t >> 4, q = t & 15;
  const int i = i0 + r;
  float l = 0.f;
#pragma unroll
  for (int p = 0; p < 4; ++p) l += lp[(size_t)p * NN + i];
  const float rl = 1.0f / l;
  f32x4 ya = {0, 0, 0, 0};
#pragma unroll
  for (int p = 0; p < 4; ++p)
    ya += *(const f32x4*)(Yp + ((size_t)p * NN + i) * 64 + q * 4);
  const f32x4 h1 = *(const f32x4*)(H1 + (size_t)i * 64 + q * 4);
#pragma unroll
  for (int c = 0; c < 4; ++c) U[r][q * 4 + c] = fmaf(ya[c], rl, h1[c]);
  __syncthreads();
  float z[4];
#pragma unroll
  for (int c = 0; c < 4; ++c) z[c] = bsv;
#pragma unroll
  for (int k4 = 0; k4 < 64; k4 += 4) {
    const f32x4 u4 = *(const f32x4*)&U[r][k4];
#pragma unroll
    for (int kk = 0; kk < 4; ++kk) {
      const f32x4 sa = *(const f32x4*)&sA[k4 + kk][q * 4];
#pragma unroll
      for (int c = 0; c < 4; ++c) z[c] = fmaf(u4[kk], sa[c], z[c]);
    }
  }
  __syncthreads();
#pragma unroll
  for (int c = 0; c < 4; ++c) U[r][q * 4 + c] = fmaxf(z[c], 0.f);
  __syncthreads();
  float hv[4];
#pragma unroll
  for (int c = 0; c < 4; ++c) hv[c] = sb2v[q * 4 + c];
#pragma unroll
  for (int k4 = 0; k4 < 64; k4 += 4) {
    const f32x4 u4 = *(const f32x4*)&U[r][k4];
#pragma unroll
    for (int kk = 0; kk < 4; ++kk) {
      const f32x4 sb4 = *(const f32x4*)&sB[k4 + kk][q * 4];
#pragma unroll
      for (int c = 0; c < 4; ++c) hv[c] = fmaf(u4[kk], sb4[c], hv[c]);
    }
  }
  __syncthreads();
#pragma unroll
  for (int c = 0; c < 4; ++c) U[r][q * 4 + c] = fmaxf(hv[c], 0.f);
  __syncthreads();
  *(f32x4*)(H2 + (size_t)i0 * 64 + (t << 2)) =
      *(const f32x4*)&U[t >> 4][(t << 2) & 63];
  const int n = t >> 2, sg = (t & 3) * 4;
  h4 v;
#pragma unroll
  for (int ss = 0; ss < 4; ss++) v[ss] = (_Float16)U[sg + ss][n];
  *(h4*)(HT2 + (size_t)n * NN + i0 + sg) = v;
}

// ---------------------------------------------------------------------------
// final: V = relu((sum(Ypart)/l + H2)@wt2 + bs2); column sums -> atomicAdd.
// ---------------------------------------------------------------------------
__global__ __launch_bounds__(256) void final_kernel(
    const float* __restrict__ Yp, const float* __restrict__ lp,
    const float* __restrict__ H2, const float* __restrict__ wt2,
    const float* __restrict__ bs2, float* __restrict__ svec)
{
  __shared__ float sA[64][68];
  __shared__ float U[16][68];
  __shared__ float cred[4][64];
  const int t = threadIdx.x;
  for (int e = t; e < 1024; e += 256) {
    const int rr = e >> 4, cc = (e << 2) & 63;
    *(f32x4*)&sA[rr][cc] = *(const f32x4*)(wt2 + (e << 2));
  }
  const float bsv = bs2[0];
  const int i0 = blockIdx.x * 16;
  const int r = t >> 4, q = t & 15;
  const int i = i0 + r;
  float l = 0.f;
#pragma unroll
  for (int p = 0; p < 4; ++p) l += lp[(size_t)p * NN + i];
  const float rl = 1.0f / l;
  f32x4 ya = {0, 0, 0, 0};
#pragma unroll
  for (int p = 0; p < 4; ++p)
    ya += *(const f32x4*)(Yp + ((size_t)p * NN + i) * 64 + q * 4);
  const f32x4 h2 = *(const f32x4*)(H2 + (size_t)i * 64 + q * 4);
#pragma unroll
  for (int c = 0; c < 4; ++c) U[r][q * 4 + c] = fmaf(ya[c], rl, h2[c]);
  __syncthreads();
  float z[4];
#pragma unroll
  for (int c = 0; c < 4; ++c) z[c] = bsv;
#pragma unroll
  for (int k4 = 0; k4 < 64; k4 += 4) {
    const f32x4 u4 = *(const f32x4*)&U[r][k4];
#pragma unroll
    for (int kk = 0; kk < 4; ++kk) {
      const f32x4 sa = *(const f32x4*)&sA[k4 + kk][q * 4];
#pragma unroll
      for (int c = 0; c < 4; ++c) z[c] = fmaf(u4[kk], sa[c], z[c]);
    }
  }
  __syncthreads();
#pragma unroll
  for (int c = 0; c < 4; ++c) U[r][q * 4 + c] = fmaxf(z[c], 0.f);
  __syncthreads();
  const int col = t & 63, rg = t >> 6;
  float ps = 0.f;
#pragma unroll
  for (int rr = 0; rr < 4; rr++) ps += U[rg * 4 + rr][col];
  cred[rg][col] = ps;
  __syncthreads();
  if (t < 64)
    atomicAdd(svec + t, cred[0][t] + cred[1][t] + cred[2][t] + cred[3][t]);
}

__global__ void out_kernel(const float* __restrict__ svec,
                           const float* __restrict__ Wl,
                           const float* __restrict__ bl,
                           float* __restrict__ out)
{
  const int t = threadIdx.x;  // 64 threads
  float v = svec[t] * Wl[t];
#pragma unroll
  for (int off = 32; off > 0; off >>= 1) v += __shfl_down(v, off);
  if (t == 0) {
    const float logit = v + bl[0];
    out[0] = 1.0f / (1.0f + __builtin_amdgcn_exp2f(-logit * L2E));
  }
}

extern "C" void kernel_launch(void* const* d_in, const int* in_sizes, int n_in,
                              void* d_out, int out_size, void* d_ws,
                              size_t ws_size, hipStream_t stream)
{
  const float* x     = (const float*)d_in[0];
  const float* alpha = (const float*)d_in[1];
  const float* W1    = (const float*)d_in[2];
  const float* b1    = (const float*)d_in[3];
  const float* wt1   = (const float*)d_in[4];
  const float* bs1   = (const float*)d_in[5];
  const float* W2    = (const float*)d_in[6];
  const float* b2    = (const float*)d_in[7];
  const float* wt2   = (const float*)d_in[8];
  const float* bs2   = (const float*)d_in[9];
  const float* Wl    = (const float*)d_in[10];
  const float* bl    = (const float*)d_in[11];
  float* out = (float*)d_out;

  char* ws = (char*)d_ws;
  size_t off = 0;
  auto alloc = [&](size_t bytes) {
    void* p = ws + off;
    off = (off + bytes + 255) & ~(size_t)255;
    return p;
  };
  float* eta_s = (float*)alloc(NN * 4 + 256);
  float* phi_s = (float*)alloc(NN * 4 + 256);
  float* H1    = (float*)alloc((size_t)NN * 64 * 4);
  float* H2    = (float*)alloc((size_t)NN * 64 * 4);
  float* Ypart = (float*)alloc((size_t)4 * NN * 64 * 4);   // 8 MB
  float* lpart = (float*)alloc((size_t)4 * NN * 4);
  _Float16* HT = (_Float16*)alloc((size_t)NN * 64 * 2 + 512);
  float* svec  = (float*)alloc(64 * 4);
  unsigned char* Pm8 = (unsigned char*)alloc((size_t)NN * NN);  // 64 MB

  prep_kernel<<<256, 256, 0, stream>>>(x, alpha, W1, b1, eta_s, phi_s, H1, HT, svec);
  attn_pass<true><<<1024, 256, 0, stream>>>(eta_s, phi_s, HT, alpha, Pm8, Ypart, lpart);
  mid_kernel<<<512, 256, 0, stream>>>(Ypart, lpart, H1, wt1, bs1, W2, b2, H2, HT);
  attn_pass<false><<<1024, 256, 0, stream>>>(eta_s, phi_s, HT, alpha, Pm8, Ypart, nullptr);
  final_kernel<<<512, 256, 0, stream>>>(Ypart, lpart, H2, wt2, bs2, svec);
  out_kernel<<<1, 64, 0, stream>>>(svec, Wl, bl, out);
}

// Round 11
// 157.526 us; speedup vs baseline: 1.0363x; 1.0363x over previous
//
#include <hip/hip_runtime.h>
#include <math.h>

#define NN 8192
#define L2E 1.44269504088896340736f
#define TWO_PI 6.28318530717958647693f

typedef _Float16 h8 __attribute__((ext_vector_type(8)));
typedef _Float16 h4 __attribute__((ext_vector_type(4)));
typedef float f32x4 __attribute__((ext_vector_type(4)));
typedef float f32x2 __attribute__((ext_vector_type(2)));
typedef unsigned int u32x4 __attribute__((ext_vector_type(4)));
#define MFMA16(A, B, C) __builtin_amdgcn_mfma_f32_16x16x32_f16(A, B, C, 0, 0, 0)

// async 16B-per-lane global->LDS DMA; LDS dest is wave-uniform base + lane*16
#define GLD_LDS16(gsrc, ldst)                                          \
  __builtin_amdgcn_global_load_lds(                                    \
      (const __attribute__((address_space(1))) unsigned int*)(gsrc),   \
      (__attribute__((address_space(3))) unsigned int*)(ldst), 16, 0, 0)

union V8 { float4 v[2]; float f[8]; };

// ---------------------------------------------------------------------------
// prep: eta_s = eta*s, phi_s = phi*s (s = sqrt(alpha*log2e));
// H1 = relu(x@W1+b1) f32 row-major + f16 transposed [64][NN]. 32 rows/block.
// ---------------------------------------------------------------------------
__global__ __launch_bounds__(256) void prep_kernel(
    const float* __restrict__ x, const float* __restrict__ alpha,
    const float* __restrict__ W1, const float* __restrict__ b1,
    float* __restrict__ eta_s, float* __restrict__ phi_s,
    float* __restrict__ H1, _Float16* __restrict__ HT1,
    float* __restrict__ svec)
{
  __shared__ float sW[448];
  __shared__ float sb[64];
  __shared__ float T[32][68];
  const int t = threadIdx.x;
  if (blockIdx.x == 0 && t < 64) svec[t] = 0.f;
  for (int k = t; k < 448; k += 256) sW[k] = W1[k];
  if (t < 64) sb[t] = b1[t];
  const float s = sqrtf(alpha[0] * L2E);
  const int i0 = blockIdx.x * 32;
  const int r = t >> 3, q = t & 7;
  const int i = i0 + r;
  float xv[7];
#pragma unroll
  for (int k = 0; k < 7; k++) xv[k] = x[i * 7 + k];
  if (q == 0) { eta_s[i] = xv[1] * s; phi_s[i] = xv[2] * s; }
  __syncthreads();
#pragma unroll
  for (int c = 0; c < 8; c++) {
    const int n = q * 8 + c;
    float hv = sb[n];
#pragma unroll
    for (int k = 0; k < 7; k++) hv = fmaf(xv[k], sW[k * 64 + n], hv);
    T[r][n] = fmaxf(hv, 0.f);
  }
  __syncthreads();
  for (int e = t; e < 512; e += 256)
    *(f32x4*)(H1 + (size_t)i0 * 64 + (e << 2)) =
        *(const f32x4*)&T[e >> 4][(e << 2) & 63];
  const int n = t >> 2, sg = (t & 3) * 8;
  h8 v;
#pragma unroll
  for (int ss = 0; ss < 8; ss++) v[ss] = (_Float16)T[sg + ss][n];
  *(h8*)(HT1 + (size_t)n * NN + i0 + sg) = v;
}

// ---------------------------------------------------------------------------
// attn: 32 i-rows/block, 4-way j-split (grid 1024). 16 stages of 128 j; HT
// chunk [64 rows][128 j] staged via global_load_lds into double-buffered,
// XOR-swizzled LDS. Wave w consumes j-slice w*32..w*32+31 of each stage.
// PASS1: compute P = exp(exp(-a*dR^2)-1) in f32; f16-pack feeds the MFMA
//        (Y1 += P@HT, l via ones-MFMA); ALSO fp8(e4m3)-pack and store to Pm8
//        in fragment-stream order (one 16B store/lane/stage, coalesced 1KB
//        per wave). P in (e^-1,1] -> e4m3 rel err ~1% RMS, averaged out by
//        the 8192-wide row sums downstream.
// PASS2: pure GEMM — fp8 frags reloaded (64 MB), expanded fp8->f32->f16 on
//        the idle VALU pipe, prefetched ~1.5 stages ahead; no eta/phi/exp2.
// ---------------------------------------------------------------------------
template <bool PASS1>
__global__ __launch_bounds__(256, 4) void attn_pass(
    const float* __restrict__ eta_s, const float* __restrict__ phi_s,
    const _Float16* __restrict__ HT, const float* __restrict__ alpha,
    unsigned char* __restrict__ Pm8,
    float* __restrict__ Ypart, float* __restrict__ lpart)
{
  __shared__ __align__(16) char smem[32768];
  _Float16* stage = (_Float16*)smem;  // 2 x 16384 B
  const int tid = threadIdx.x;
  const int w = tid >> 6, lane = tid & 63, m = lane & 15, g = lane >> 4;
  const int tile = blockIdx.x >> 2, part = blockIdx.x & 3;
  const int i0 = tile << 5;
  const int jbase = part << 11;
  const int jcol0 = jbase + (w << 5) + (g << 3);  // this lane's j-group base

  // staging geometry: slot d = k*256+tid holds HT row (k*16 + tid>>4),
  // swizzled j-group ((tid&15) ^ (tid>>4)). Same swizzle offset for all k.
  const int r0 = tid >> 4, gq = tid & 15;
  const _Float16* sbase = HT + (size_t)r0 * NN + ((gq ^ r0) << 3) + jbase;

  f32x4 a00 = {0,0,0,0}, a01 = {0,0,0,0}, a02 = {0,0,0,0}, a03 = {0,0,0,0};
  f32x4 a10 = {0,0,0,0}, a11 = {0,0,0,0}, a12 = {0,0,0,0}, a13 = {0,0,0,0};
  f32x4 l0a = {0,0,0,0}, l1a = {0,0,0,0};
  const h8 onesv = {(_Float16)1.f, (_Float16)1.f, (_Float16)1.f, (_Float16)1.f,
                    (_Float16)1.f, (_Float16)1.f, (_Float16)1.f, (_Float16)1.f};

  // fp8 fragment-stream base: block*(16 stages * 4 KB) + wave*1 KB + lane*16B
  // stage s at pfb8 + s*4096; one u32x4 = af0(8B) || af1(8B).
  unsigned char* const pfb8 =
      Pm8 + ((size_t)blockIdx.x * 16) * 4096 + (w << 10) + (lane << 4);

  // PASS1 state: eta/phi of i-rows + register-prefetched j-slices
  float Cs = 0.f, et0 = 0.f, ph0 = 0.f, et1 = 0.f, ph1 = 0.f;
  const float* ep = nullptr;
  const float* pp = nullptr;
  V8 E0, P0, E1, P1;
  // PASS2 state: register-prefetched fp8 A-frags (even/odd stages)
  u32x4 pe8, po8;
  if constexpr (PASS1) {
    Cs = TWO_PI * sqrtf(alpha[0] * L2E);
    et0 = eta_s[i0 + m];      ph0 = phi_s[i0 + m];
    et1 = eta_s[i0 + 16 + m]; ph1 = phi_s[i0 + 16 + m];
    ep = eta_s + jcol0;
    pp = phi_s + jcol0;
    E0.v[0] = *(const float4*)ep;  E0.v[1] = *(const float4*)(ep + 4);
    P0.v[0] = *(const float4*)pp;  P0.v[1] = *(const float4*)(pp + 4);
  } else {
    pe8 = *(const u32x4*)(pfb8);
    po8 = *(const u32x4*)(pfb8 + 4096);
  }

  // prologue: stage 0 -> buf0
#pragma unroll
  for (int k = 0; k < 4; ++k)
    GLD_LDS16(sbase + (size_t)k * 16 * NN, stage + ((k * 256 + tid) << 3));
  __syncthreads();

  // frag slot (nb=0): row block m, swizzled j-group (w*4+g)^m
  const int fs = ((m << 4) + (((w << 2) | g) ^ m)) << 3;

  union AF { h8 v; decltype(__builtin_amdgcn_cvt_pkrtz(0.f, 0.f)) p[4]; };

  // PASS1 body: pv chain -> f16 pack (MFMA) + fp8 pack (store) -> MFMA (+l)
  auto stage_compute = [&](const V8& Ec, const V8& Pc, const _Float16* cur,
                           int sIdx) {
    const h8 b0 = *(const h8*)(cur + fs);
    const h8 b1 = *(const h8*)(cur + 2048 + fs);
    const h8 b2 = *(const h8*)(cur + 4096 + fs);
    const h8 b3 = *(const h8*)(cur + 6144 + fs);
    AF af0, af1;
    float pva[8], pvb[8];
#pragma unroll
    for (int tt = 0; tt < 8; tt += 2) {
      const f32x2 pj = {Pc.f[tt], Pc.f[tt + 1]};
      const f32x2 ej = {Ec.f[tt], Ec.f[tt + 1]};
      const f32x2 dp0 = ph0 - pj, dp1 = ph1 - pj;
      const f32x2 ad0 = {fabsf(dp0.x), fabsf(dp0.y)};
      const f32x2 ad1 = {fabsf(dp1.x), fabsf(dp1.y)};
      const f32x2 cm0 = Cs - ad0, cm1 = Cs - ad1;
      const f32x2 wr0 = {fminf(ad0.x, cm0.x), fminf(ad0.y, cm0.y)};
      const f32x2 wr1 = {fminf(ad1.x, cm1.x), fminf(ad1.y, cm1.y)};
      const f32x2 de0 = et0 - ej, de1 = et1 - ej;
      const f32x2 r20 = de0 * de0 + wr0 * wr0;
      const f32x2 r21 = de1 * de1 + wr1 * wr1;
      const f32x2 ax0 = {__builtin_amdgcn_exp2f(-r20.x),
                         __builtin_amdgcn_exp2f(-r20.y)};
      const f32x2 ax1 = {__builtin_amdgcn_exp2f(-r21.x),
                         __builtin_amdgcn_exp2f(-r21.y)};
      const f32x2 ga0 = ax0 * L2E - L2E;
      const f32x2 ga1 = ax1 * L2E - L2E;
      const float va0 = __builtin_amdgcn_exp2f(ga0.x);
      const float va1 = __builtin_amdgcn_exp2f(ga0.y);
      const float vb0 = __builtin_amdgcn_exp2f(ga1.x);
      const float vb1 = __builtin_amdgcn_exp2f(ga1.y);
      pva[tt] = va0; pva[tt + 1] = va1;
      pvb[tt] = vb0; pvb[tt + 1] = vb1;
      af0.p[tt >> 1] = __builtin_amdgcn_cvt_pkrtz(va0, va1);
      af1.p[tt >> 1] = __builtin_amdgcn_cvt_pkrtz(vb0, vb1);
    }
    // fp8 pack + one 16B coalesced store (literal word-sel per ImmArg rules)
    unsigned int ra0 = __builtin_amdgcn_cvt_pk_fp8_f32(pva[0], pva[1], 0, false);
    ra0 = __builtin_amdgcn_cvt_pk_fp8_f32(pva[2], pva[3], ra0, true);
    unsigned int ra1 = __builtin_amdgcn_cvt_pk_fp8_f32(pva[4], pva[5], 0, false);
    ra1 = __builtin_amdgcn_cvt_pk_fp8_f32(pva[6], pva[7], ra1, true);
    unsigned int rb0 = __builtin_amdgcn_cvt_pk_fp8_f32(pvb[0], pvb[1], 0, false);
    rb0 = __builtin_amdgcn_cvt_pk_fp8_f32(pvb[2], pvb[3], rb0, true);
    unsigned int rb1 = __builtin_amdgcn_cvt_pk_fp8_f32(pvb[4], pvb[5], 0, false);
    rb1 = __builtin_amdgcn_cvt_pk_fp8_f32(pvb[6], pvb[7], rb1, true);
    const u32x4 r8 = {ra0, ra1, rb0, rb1};
    *(u32x4*)(pfb8 + sIdx * 4096) = r8;
    __builtin_amdgcn_s_setprio(1);
    a00 = MFMA16(af0.v, b0, a00); a01 = MFMA16(af0.v, b1, a01);
    a02 = MFMA16(af0.v, b2, a02); a03 = MFMA16(af0.v, b3, a03);
    a10 = MFMA16(af1.v, b0, a10); a11 = MFMA16(af1.v, b1, a11);
    a12 = MFMA16(af1.v, b2, a12); a13 = MFMA16(af1.v, b3, a13);
    l0a = MFMA16(af0.v, onesv, l0a);
    l1a = MFMA16(af1.v, onesv, l1a);
    __builtin_amdgcn_s_setprio(0);
  };

  // PASS2 body: fp8 frags -> f32 -> f16 on VALU, then 8 MFMAs
  auto stage_gemm = [&](u32x4 r8, const _Float16* cur) {
    const h8 b0 = *(const h8*)(cur + fs);
    const h8 b1 = *(const h8*)(cur + 2048 + fs);
    const h8 b2 = *(const h8*)(cur + 4096 + fs);
    const h8 b3 = *(const h8*)(cur + 6144 + fs);
    AF af0, af1;
    {
      const f32x2 c01 = __builtin_amdgcn_cvt_pk_f32_fp8(r8.x, false);
      const f32x2 c23 = __builtin_amdgcn_cvt_pk_f32_fp8(r8.x, true);
      const f32x2 c45 = __builtin_amdgcn_cvt_pk_f32_fp8(r8.y, false);
      const f32x2 c67 = __builtin_amdgcn_cvt_pk_f32_fp8(r8.y, true);
      af0.p[0] = __builtin_amdgcn_cvt_pkrtz(c01.x, c01.y);
      af0.p[1] = __builtin_amdgcn_cvt_pkrtz(c23.x, c23.y);
      af0.p[2] = __builtin_amdgcn_cvt_pkrtz(c45.x, c45.y);
      af0.p[3] = __builtin_amdgcn_cvt_pkrtz(c67.x, c67.y);
    }
    {
      const f32x2 c01 = __builtin_amdgcn_cvt_pk_f32_fp8(r8.z, false);
      const f32x2 c23 = __builtin_amdgcn_cvt_pk_f32_fp8(r8.z, true);
      const f32x2 c45 = __builtin_amdgcn_cvt_pk_f32_fp8(r8.w, false);
      const f32x2 c67 = __builtin_amdgcn_cvt_pk_f32_fp8(r8.w, true);
      af1.p[0] = __builtin_amdgcn_cvt_pkrtz(c01.x, c01.y);
      af1.p[1] = __builtin_amdgcn_cvt_pkrtz(c23.x, c23.y);
      af1.p[2] = __builtin_amdgcn_cvt_pkrtz(c45.x, c45.y);
      af1.p[3] = __builtin_amdgcn_cvt_pkrtz(c67.x, c67.y);
    }
    __builtin_amdgcn_s_setprio(1);
    a00 = MFMA16(af0.v, b0, a00); a01 = MFMA16(af0.v, b1, a01);
    a02 = MFMA16(af0.v, b2, a02); a03 = MFMA16(af0.v, b3, a03);
    a10 = MFMA16(af1.v, b0, a10); a11 = MFMA16(af1.v, b1, a11);
    a12 = MFMA16(af1.v, b2, a12); a13 = MFMA16(af1.v, b3, a13);
    __builtin_amdgcn_s_setprio(0);
  };

#pragma unroll
  for (int s2 = 0; s2 < 8; ++s2) {
    // body A: compute stage 2*s2 from buf0; prefetch stage 2*s2+1 -> buf1
    {
      const _Float16* src = sbase + (2 * s2 + 1) * 128;
#pragma unroll
      for (int k = 0; k < 4; ++k)
        GLD_LDS16(src + (size_t)k * 16 * NN,
                  stage + 8192 + ((k * 256 + tid) << 3));
      if constexpr (PASS1) {
        E1.v[0] = *(const float4*)(ep + s2 * 256 + 128);
        E1.v[1] = *(const float4*)(ep + s2 * 256 + 132);
        P1.v[0] = *(const float4*)(pp + s2 * 256 + 128);
        P1.v[1] = *(const float4*)(pp + s2 * 256 + 132);
        stage_compute(E0, P0, stage, 2 * s2);
      } else {
        const u32x4 c = pe8;
        if (s2 < 7) {  // prefetch next even stage (used in ~1.5 stages)
          pe8 = *(const u32x4*)(pfb8 + (2 * s2 + 2) * 4096);
        }
        stage_gemm(c, stage);
      }
      __syncthreads();  // drains prefetch + all frag reads of buf0
    }
    // body B: compute stage 2*s2+1 from buf1; prefetch 2*s2+2 -> buf0
    {
      if (s2 < 7) {
        const _Float16* src = sbase + (2 * s2 + 2) * 128;
#pragma unroll
        for (int k = 0; k < 4; ++k)
          GLD_LDS16(src + (size_t)k * 16 * NN,
                    stage + ((k * 256 + tid) << 3));
        if constexpr (PASS1) {
          E0.v[0] = *(const float4*)(ep + s2 * 256 + 256);
          E0.v[1] = *(const float4*)(ep + s2 * 256 + 260);
          P0.v[0] = *(const float4*)(pp + s2 * 256 + 256);
          P0.v[1] = *(const float4*)(pp + s2 * 256 + 260);
        }
      }
      if constexpr (PASS1) {
        stage_compute(E1, P1, stage + 8192, 2 * s2 + 1);
      } else {
        const u32x4 c = po8;
        if (s2 < 7) {  // prefetch next odd stage
          po8 = *(const u32x4*)(pfb8 + (2 * s2 + 3) * 4096);
        }
        stage_gemm(c, stage + 8192);
      }
      __syncthreads();
    }
  }

  // cross-wave reduction (aliases stage; all stage reads completed above).
  // D layout: col = lane&15, row = (lane>>4)*4 + reg. Col 64 carries l
  // (= rowsum from the ones-MFMA; identical across lanes m, so m==0 writes).
  typedef float Red2[32][66];
  Red2* red = (Red2*)smem;                  // 2 x 8448 B
  const int h = w >> 1;
  if ((w & 1) == 0) {
#pragma unroll
    for (int r = 0; r < 4; ++r) {
      red[h][g * 4 + r][m]      = a00[r]; red[h][g * 4 + r][16 + m] = a01[r];
      red[h][g * 4 + r][32 + m] = a02[r]; red[h][g * 4 + r][48 + m] = a03[r];
      red[h][16 + g * 4 + r][m]      = a10[r]; red[h][16 + g * 4 + r][16 + m] = a11[r];
      red[h][16 + g * 4 + r][32 + m] = a12[r]; red[h][16 + g * 4 + r][48 + m] = a13[r];
    }
    if constexpr (PASS1) {
      if (m == 0) {
#pragma unroll
        for (int r = 0; r < 4; ++r) {
          red[h][g * 4 + r][64]      = l0a[r];
          red[h][16 + g * 4 + r][64] = l1a[r];
        }
      }
    }
  }
  __syncthreads();
  if (w & 1) {
#pragma unroll
    for (int r = 0; r < 4; ++r) {
      red[h][g * 4 + r][m]      += a00[r]; red[h][g * 4 + r][16 + m] += a01[r];
      red[h][g * 4 + r][32 + m] += a02[r]; red[h][g * 4 + r][48 + m] += a03[r];
      red[h][16 + g * 4 + r][m]      += a10[r]; red[h][16 + g * 4 + r][16 + m] += a11[r];
      red[h][16 + g * 4 + r][32 + m] += a12[r]; red[h][16 + g * 4 + r][48 + m] += a13[r];
    }
    if constexpr (PASS1) {
      if (m == 0) {
#pragma unroll
        for (int r = 0; r < 4; ++r) {
          red[h][g * 4 + r][64]      += l0a[r];
          red[h][16 + g * 4 + r][64] += l1a[r];
        }
      }
    }
  }
  __syncthreads();
#pragma unroll
  for (int k = 0; k < 8; ++k) {
    const int e = tid + k * 256;
    Ypart[((size_t)part * NN + i0 + (e >> 6)) * 64 + (e & 63)] =
        red[0][e >> 6][e & 63] + red[1][e >> 6][e & 63];
  }
  if constexpr (PASS1) {
    if (tid < 32)
      lpart[(size_t)part * NN + i0 + tid] = red[0][tid][64] + red[1][tid][64];
  }
}

// ---------------------------------------------------------------------------
// mid: U = sum(Ypart)/l + H1 ; Z = relu(U@wt1+bs1) ; H2 = relu(Z@W2+b2)
// 16 rows/block, grid 512. U rows read as ds_read_b128 (U padded to [68]).
// ---------------------------------------------------------------------------
__global__ __launch_bounds__(256) void mid_kernel(
    const float* __restrict__ Yp, const float* __restrict__ lp,
    const float* __restrict__ H1, const float* __restrict__ wt1,
    const float* __restrict__ bs1, const float* __restrict__ W2,
    const float* __restrict__ b2, float* __restrict__ H2,
    _Float16* __restrict__ HT2)
{
  __shared__ float sA[64][68];
  __shared__ float sB[64][68];
  __shared__ float U[16][68];
  __shared__ float sb2v[64];
  const int t = threadIdx.x;
  for (int e = t; e < 1024; e += 256) {
    const int rr = e >> 4, cc = (e << 2) & 63;
    *(f32x4*)&sA[rr][cc] = *(const f32x4*)(wt1 + (e << 2));
    *(f32x4*)&sB[rr][cc] = *(const f32x4*)(W2 + (e << 2));
  }
  if (t < 64) sb2v[t] = b2[t];
  const float bsv = bs1[0];
  const int i0 = blockIdx.x * 16;
  const int r = t >> 4, q = t & 15;
  const int i = i0 + r;
  float l = 0.f;
#pragma unroll
  for (int p = 0; p < 4; ++p) l += lp[(size_t)p * NN + i];
  const float rl = 1.0f / l;
  f32x4 ya = {0, 0, 0, 0};
#pragma unroll
  for (int p = 0; p < 4; ++p)
    ya += *(const f32x4*)(Yp + ((size_t)p * NN + i) * 64 + q * 4);
  const f32x4 h1 = *(const f32x4*)(H1 + (size_t)i * 64 + q * 4);
#pragma unroll
  for (int c = 0; c < 4; ++c) U[r][q * 4 + c] = fmaf(ya[c], rl, h1[c]);
  __syncthreads();
  float z[4];
#pragma unroll
  for (int c = 0; c < 4; ++c) z[c] = bsv;
#pragma unroll
  for (int k4 = 0; k4 < 64; k4 += 4) {
    const f32x4 u4 = *(const f32x4*)&U[r][k4];
#pragma unroll
    for (int kk = 0; kk < 4; ++kk) {
      const f32x4 sa = *(const f32x4*)&sA[k4 + kk][q * 4];
#pragma unroll
      for (int c = 0; c < 4; ++c) z[c] = fmaf(u4[kk], sa[c], z[c]);
    }
  }
  __syncthreads();
#pragma unroll
  for (int c = 0; c < 4; ++c) U[r][q * 4 + c] = fmaxf(z[c], 0.f);
  __syncthreads();
  float hv[4];
#pragma unroll
  for (int c = 0; c < 4; ++c) hv[c] = sb2v[q * 4 + c];
#pragma unroll
  for (int k4 = 0; k4 < 64; k4 += 4) {
    const f32x4 u4 = *(const f32x4*)&U[r][k4];
#pragma unroll
    for (int kk = 0; kk < 4; ++kk) {
      const f32x4 sb4 = *(const f32x4*)&sB[k4 + kk][q * 4];
#pragma unroll
      for (int c = 0; c < 4; ++c) hv[c] = fmaf(u4[kk], sb4[c], hv[c]);
    }
  }
  __syncthreads();
#pragma unroll
  for (int c = 0; c < 4; ++c) U[r][q * 4 + c] = fmaxf(hv[c], 0.f);
  __syncthreads();
  *(f32x4*)(H2 + (size_t)i0 * 64 + (t << 2)) =
      *(const f32x4*)&U[t >> 4][(t << 2) & 63];
  const int n = t >> 2, sg = (t & 3) * 4;
  h4 v;
#pragma unroll
  for (int ss = 0; ss < 4; ss++) v[ss] = (_Float16)U[sg + ss][n];
  *(h4*)(HT2 + (size_t)n * NN + i0 + sg) = v;
}

// ---------------------------------------------------------------------------
// final: V = relu((sum(Ypart)/l + H2)@wt2 + bs2); column sums -> atomicAdd.
// ---------------------------------------------------------------------------
__global__ __launch_bounds__(256) void final_kernel(
    const float* __restrict__ Yp, const float* __restrict__ lp,
    const float* __restrict__ H2, const float* __restrict__ wt2,
    const float* __restrict__ bs2, float* __restrict__ svec)
{
  __shared__ float sA[64][68];
  __shared__ float U[16][68];
  __shared__ float cred[4][64];
  const int t = threadIdx.x;
  for (int e = t; e < 1024; e += 256) {
    const int rr = e >> 4, cc = (e << 2) & 63;
    *(f32x4*)&sA[rr][cc] = *(const f32x4*)(wt2 + (e << 2));
  }
  const float bsv = bs2[0];
  const int i0 = blockIdx.x * 16;
  const int r = t >> 4, q = t & 15;
  const int i = i0 + r;
  float l = 0.f;
#pragma unroll
  for (int p = 0; p < 4; ++p) l += lp[(size_t)p * NN + i];
  const float rl = 1.0f / l;
  f32x4 ya = {0, 0, 0, 0};
#pragma unroll
  for (int p = 0; p < 4; ++p)
    ya += *(const f32x4*)(Yp + ((size_t)p * NN + i) * 64 + q * 4);
  const f32x4 h2 = *(const f32x4*)(H2 + (size_t)i * 64 + q * 4);
#pragma unroll
  for (int c = 0; c < 4; ++c) U[r][q * 4 + c] = fmaf(ya[c], rl, h2[c]);
  __syncthreads();
  float z[4];
#pragma unroll
  for (int c = 0; c < 4; ++c) z[c] = bsv;
#pragma unroll
  for (int k4 = 0; k4 < 64; k4 += 4) {
    const f32x4 u4 = *(const f32x4*)&U[r][k4];
#pragma unroll
    for (int kk = 0; kk < 4; ++kk) {
      const f32x4 sa = *(const f32x4*)&sA[k4 + kk][q * 4];
#pragma unroll
      for (int c = 0; c < 4; ++c) z[c] = fmaf(u4[kk], sa[c], z[c]);
    }
  }
  __syncthreads();
#pragma unroll
  for (int c = 0; c < 4; ++c) U[r][q * 4 + c] = fmaxf(z[c], 0.f);
  __syncthreads();
  const int col = t & 63, rg = t >> 6;
  float ps = 0.f;
#pragma unroll
  for (int rr = 0; rr < 4; rr++) ps += U[rg * 4 + rr][col];
  cred[rg][col] = ps;
  __syncthreads();
  if (t < 64)
    atomicAdd(svec + t, cred[0][t] + cred[1][t] + cred[2][t] + cred[3][t]);
}

__global__ void out_kernel(const float* __restrict__ svec,
                           const float* __restrict__ Wl,
                           const float* __restrict__ bl,
                           float* __restrict__ out)
{
  const int t = threadIdx.x;  // 64 threads
  float v = svec[t] * Wl[t];
#pragma unroll
  for (int off = 32; off > 0; off >>= 1) v += __shfl_down(v, off);
  if (t == 0) {
    const float logit = v + bl[0];
    out[0] = 1.0f / (1.0f + __builtin_amdgcn_exp2f(-logit * L2E));
  }
}

extern "C" void kernel_launch(void* const* d_in, const int* in_sizes, int n_in,
                              void* d_out, int out_size, void* d_ws,
                              size_t ws_size, hipStream_t stream)
{
  const float* x     = (const float*)d_in[0];
  const float* alpha = (const float*)d_in[1];
  const float* W1    = (const float*)d_in[2];
  const float* b1    = (const float*)d_in[3];
  const float* wt1   = (const float*)d_in[4];
  const float* bs1   = (const float*)d_in[5];
  const float* W2    = (const float*)d_in[6];
  const float* b2    = (const float*)d_in[7];
  const float* wt2   = (const float*)d_in[8];
  const float* bs2   = (const float*)d_in[9];
  const float* Wl    = (const float*)d_in[10];
  const float* bl    = (const float*)d_in[11];
  float* out = (float*)d_out;

  char* ws = (char*)d_ws;
  size_t off = 0;
  auto alloc = [&](size_t bytes) {
    void* p = ws + off;
    off = (off + bytes + 255) & ~(size_t)255;
    return p;
  };
  float* eta_s = (float*)alloc(NN * 4 + 256);
  float* phi_s = (float*)alloc(NN * 4 + 256);
  float* H1    = (float*)alloc((size_t)NN * 64 * 4);
  float* H2    = (float*)alloc((size_t)NN * 64 * 4);
  float* Ypart = (float*)alloc((size_t)4 * NN * 64 * 4);   // 8 MB
  float* lpart = (float*)alloc((size_t)4 * NN * 4);
  _Float16* HT = (_Float16*)alloc((size_t)NN * 64 * 2 + 512);
  float* svec  = (float*)alloc(64 * 4);
  unsigned char* Pm8 = (unsigned char*)alloc((size_t)NN * NN);  // 64 MB

  prep_kernel<<<256, 256, 0, stream>>>(x, alpha, W1, b1, eta_s, phi_s, H1, HT, svec);
  attn_pass<true><<<1024, 256, 0, stream>>>(eta_s, phi_s, HT, alpha, Pm8, Ypart, lpart);
  mid_kernel<<<512, 256, 0, stream>>>(Ypart, lpart, H1, wt1, bs1, W2, b2, H2, HT);
  attn_pass<false><<<1024, 256, 0, stream>>>(eta_s, phi_s, HT, alpha, Pm8, Ypart, nullptr);
  final_kernel<<<512, 256, 0, stream>>>(Ypart, lpart, H2, wt2, bs2, svec);
  out_kernel<<<1, 64, 0, stream>>>(svec, Wl, bl, out);
}